// Round 1
// baseline (267979.565 us; speedup 1.0000x reference)
//
#include <hip/hip_runtime.h>
#include <math.h>

#define T_STEPS 16384
#define IN 512
#define HID 1024
#define NC 512
#define NWG 512
#define TPB 256
#define ROWS_PER_WG 8   // 4096 gate rows / 512 WGs
#define HPW 2           // h elements per WG = 1024/512
#define KTOT 1536       // IN + HID
#define KPAD 1544       // padded LDS row stride (floats): rows land on distinct banks
#define TT 8            // t-rows per block in dense kernel

__device__ __forceinline__ float sigmoidf_(float x) { return 1.f / (1.f + expf(-x)); }

// ---------------- Kernel 1: persistent LSTM recurrence ----------------
__global__ __launch_bounds__(TPB, 2) void lstm_rec(
    const float* __restrict__ X,     // [T, IN]
    const float* __restrict__ h0,    // [HID]
    const float* __restrict__ c0,    // [HID]
    const float* __restrict__ W_ih,  // [4H, IN]
    const float* __restrict__ W_hh,  // [4H, HID]
    const float* __restrict__ b_ih,  // [4H]
    const float* __restrict__ b_hh,  // [4H]
    float* __restrict__ h_all,       // ws [T, HID]
    float* __restrict__ hbuf,        // ws [2, HID]
    unsigned int* __restrict__ ctr,  // ws [T] zeroed
    unsigned int* __restrict__ abortf)
{
    __shared__ float w[ROWS_PER_WG][KPAD];   // ~49.4 KB
    __shared__ float sv[KTOT];               // 6 KB
    __shared__ float gacc[ROWS_PER_WG];

    const int tid = threadIdx.x;
    const int wg  = blockIdx.x;
    const int hbase = wg * HPW;

    // --- stage this WG's weight rows into LDS (once) ---
    for (int rl = 0; rl < ROWS_PER_WG; ++rl) {
        const int q = rl >> 1, jh = rl & 1;
        const int row = q * HID + hbase + jh;
        for (int k = tid; k < IN; k += TPB)  w[rl][k]       = W_ih[(size_t)row * IN + k];
        for (int k = tid; k < HID; k += TPB) w[rl][IN + k]  = W_hh[(size_t)row * HID + k];
    }

    const int g  = tid & 31;   // 32 threads per row
    const int rl = tid >> 5;   // 0..7
    const int q_  = rl >> 1, jh_ = rl & 1;
    const int row_ = q_ * HID + hbase + jh_;
    const float bias = b_ih[row_] + b_hh[row_];

    float c_state = 0.f;
    if (tid < HPW) c_state = c0[hbase + tid];
    __syncthreads();

    for (int t = 0; t < T_STEPS; ++t) {
        // stage [x_t, h_{t-1}] into LDS
        const float* xr = X + (size_t)t * IN;
        for (int k = tid; k < IN; k += TPB) sv[k] = xr[k];
        const float* hsrc = (t == 0) ? h0 : (hbuf + (size_t)(t & 1) * HID);
        for (int k = tid; k < HID; k += TPB)
            sv[IN + k] = __hip_atomic_load(const_cast<float*>(&hsrc[k]),
                                           __ATOMIC_RELAXED, __HIP_MEMORY_SCOPE_AGENT);
        __syncthreads();

        // 8 dot products of length 1536, 32 lanes each, stride-128 interleave
        float acc = 0.f;
        #pragma unroll
        for (int j = 0; j < 12; ++j) {
            const int k = g * 4 + j * 128;
            const float4 wv = *(const float4*)&w[rl][k];
            const float4 xv = *(const float4*)&sv[k];
            acc += wv.x * xv.x + wv.y * xv.y + wv.z * xv.z + wv.w * xv.w;
        }
        #pragma unroll
        for (int off = 16; off; off >>= 1) acc += __shfl_xor(acc, off);
        if (g == 0) gacc[rl] = acc + bias;
        __syncthreads();

        if (tid < HPW) {
            const float iv = sigmoidf_(gacc[0 * HPW + tid]);
            const float fv = sigmoidf_(gacc[1 * HPW + tid]);
            const float gv = tanhf   (gacc[2 * HPW + tid]);
            const float ov = sigmoidf_(gacc[3 * HPW + tid]);
            c_state = fv * c_state + iv * gv;
            const float h = ov * tanhf(c_state);
            h_all[(size_t)t * HID + hbase + tid] = h;
            __hip_atomic_store(&hbuf[(size_t)((t + 1) & 1) * HID + hbase + tid], h,
                               __ATOMIC_RELAXED, __HIP_MEMORY_SCOPE_AGENT);
        }
        __syncthreads();

        // device-wide barrier: per-step counter (wave 0 lane 0 issues; its release
        // fence covers lanes 0/1's write-through h stores)
        if (tid == 0) {
            __hip_atomic_fetch_add(&ctr[t], 1u, __ATOMIC_ACQ_REL, __HIP_MEMORY_SCOPE_AGENT);
            if (__hip_atomic_load(abortf, __ATOMIC_RELAXED, __HIP_MEMORY_SCOPE_AGENT) == 0u) {
                unsigned spins = 0;
                while (__hip_atomic_load(&ctr[t], __ATOMIC_ACQUIRE, __HIP_MEMORY_SCOPE_AGENT) < NWG) {
                    __builtin_amdgcn_s_sleep(2);
                    if (++spins > 1500000u) {  // ~80 ms: deadlock safety, garbage-but-terminates
                        __hip_atomic_store(abortf, 1u, __ATOMIC_RELAXED, __HIP_MEMORY_SCOPE_AGENT);
                        break;
                    }
                }
            }
        }
        __syncthreads();
    }
}

// ---------------- Kernel 2: out_t = softmax_C(h_t @ Wd^T + bd) ----------------
__global__ __launch_bounds__(256) void dense_softmax(
    const float* __restrict__ h_all, const float* __restrict__ Wd,
    const float* __restrict__ bd, float* __restrict__ P)
{
    __shared__ float hs[TT][HID];   // 32 KB
    __shared__ float ls[TT][NC];    // 16 KB
    const int tid = threadIdx.x;
    const int t0  = blockIdx.x * TT;

    for (int i = tid; i < TT * HID; i += 256)
        hs[i >> 10][i & 1023] = h_all[(size_t)t0 * HID + i];
    __syncthreads();

    const int c0 = tid, c1 = tid + 256;
    float acc0[TT], acc1[TT];
    #pragma unroll
    for (int tt = 0; tt < TT; ++tt) { acc0[tt] = 0.f; acc1[tt] = 0.f; }
    const float4* w0 = (const float4*)&Wd[(size_t)c0 * HID];
    const float4* w1 = (const float4*)&Wd[(size_t)c1 * HID];
    for (int k4 = 0; k4 < HID / 4; ++k4) {
        const float4 a = w0[k4], b = w1[k4];
        #pragma unroll
        for (int tt = 0; tt < TT; ++tt) {
            const float4 h4 = *(const float4*)&hs[tt][k4 * 4];  // broadcast across lanes
            acc0[tt] += a.x * h4.x + a.y * h4.y + a.z * h4.z + a.w * h4.w;
            acc1[tt] += b.x * h4.x + b.y * h4.y + b.z * h4.z + b.w * h4.w;
        }
    }
    const float bb0 = bd[c0], bb1 = bd[c1];
    #pragma unroll
    for (int tt = 0; tt < TT; ++tt) { ls[tt][c0] = acc0[tt] + bb0; ls[tt][c1] = acc1[tt] + bb1; }
    __syncthreads();

    // per-row softmax over NC=512: wave wv handles rows wv and wv+4
    const int lane = tid & 63, wv = tid >> 6;
    for (int rr = 0; rr < 2; ++rr) {
        const int tt = wv + rr * 4;
        float vals[8];
        float m = -1e30f;
        #pragma unroll
        for (int j = 0; j < 8; ++j) { vals[j] = ls[tt][lane + 64 * j]; m = fmaxf(m, vals[j]); }
        #pragma unroll
        for (int off = 32; off; off >>= 1) m = fmaxf(m, __shfl_xor(m, off));
        float s = 0.f;
        #pragma unroll
        for (int j = 0; j < 8; ++j) { vals[j] = expf(vals[j] - m); s += vals[j]; }
        #pragma unroll
        for (int off = 32; off; off >>= 1) s += __shfl_xor(s, off);
        const float inv = 1.f / s;
        #pragma unroll
        for (int j = 0; j < 8; ++j) P[(size_t)(t0 + tt) * NC + lane + 64 * j] = vals[j] * inv;
    }
}

// ---------------- Kernel 3a: colsum[c] = sum_t exp(P[t][c])  (p in [0,1], no max needed) ----
__global__ __launch_bounds__(256) void colsum_k(const float* __restrict__ P, float* __restrict__ cs)
{
    const int tid = threadIdx.x;
    const int c  = blockIdx.x * 16 + (tid & 15);
    const int tr = tid >> 4;  // 0..15
    float s = 0.f;
    #pragma unroll 8
    for (int t = tr; t < T_STEPS; t += 16) s += expf(P[(size_t)t * NC + c]);
    __shared__ float red[256];
    red[tid] = s; __syncthreads();
    for (int off = 128; off >= 16; off >>= 1) {
        if (tid < off) red[tid] += red[tid + off];
        __syncthreads();
    }
    if (tid < 16) cs[blockIdx.x * 16 + tid] = red[tid];
}

// ---------------- Kernel 3b: out = exp(P) / colsum ----------------
__global__ __launch_bounds__(256) void norm_k(float* P, const float* __restrict__ cs)
{
    size_t i = (size_t)blockIdx.x * 256 + threadIdx.x;
    const size_t n = (size_t)T_STEPS * NC;
    const size_t stride = (size_t)gridDim.x * 256;
    for (; i < n; i += stride) P[i] = expf(P[i]) / cs[i & (NC - 1)];
}

extern "C" void kernel_launch(void* const* d_in, const int* in_sizes, int n_in,
                              void* d_out, int out_size, void* d_ws, size_t ws_size,
                              hipStream_t stream) {
    const float* X    = (const float*)d_in[0];
    const float* h0   = (const float*)d_in[1];
    const float* c0   = (const float*)d_in[2];
    const float* W_ih = (const float*)d_in[3];
    const float* W_hh = (const float*)d_in[4];
    const float* b_ih = (const float*)d_in[5];
    const float* b_hh = (const float*)d_in[6];
    const float* Wd   = (const float*)d_in[7];
    const float* bd   = (const float*)d_in[8];
    float* out = (float*)d_out;

    char* ws = (char*)d_ws;
    unsigned int* ctr    = (unsigned int*)ws;                    // T counters + abort flag
    unsigned int* abortf = ctr + T_STEPS;
    float* hbuf  = (float*)(ws + 66560);                         // 2*HID
    float* cs    = (float*)(ws + 66560 + 8192);                  // NC
    float* h_all = (float*)(ws + 66560 + 8192 + 2048);           // T*HID

    hipMemsetAsync(ctr, 0, 66560, stream);
    lstm_rec<<<NWG, TPB, 0, stream>>>(X, h0, c0, W_ih, W_hh, b_ih, b_hh, h_all, hbuf, ctr, abortf);
    dense_softmax<<<T_STEPS / TT, 256, 0, stream>>>(h_all, Wd, bd, out);
    colsum_k<<<NC / 16, 256, 0, stream>>>(out, cs);
    norm_k<<<2048, 256, 0, stream>>>(out, cs);
}

// Round 2
// 86153.656 us; speedup vs baseline: 3.1105x; 3.1105x over previous
//
#include <hip/hip_runtime.h>
#include <math.h>

#define T_STEPS 16384
#define IN 512
#define HID 1024
#define NC 512
#define NWG 256
#define TPB 256
#define HPW 4           // h elements per WG = 1024/256
#define TT 8            // t-rows per block in dense kernel

__device__ __forceinline__ float sigmoidf_(float x) { return 1.f / (1.f + expf(-x)); }

// ---------------- Kernel 1: persistent LSTM recurrence ----------------
// 256 WGs x 256 threads, 1 WG/CU. Wave wv owns gate q=wv for this WG's 4 h
// elements (rows q*HID + hbase + jh, jh=0..3). Weights live in VGPRs:
// lane L covers k = L*4 + c*256, c=0..5 (c<2 -> x part, c>=2 -> h part).
__global__ __launch_bounds__(TPB, 1) void lstm_rec(
    const float* __restrict__ X,     // [T, IN]
    const float* __restrict__ h0,    // [HID]
    const float* __restrict__ c0,    // [HID]
    const float* __restrict__ W_ih,  // [4H, IN]
    const float* __restrict__ W_hh,  // [4H, HID]
    const float* __restrict__ b_ih,  // [4H]
    const float* __restrict__ b_hh,  // [4H]
    float* __restrict__ h_all,       // ws [T, HID]
    float* __restrict__ hbuf,        // ws [2, HID]
    unsigned int* __restrict__ done) // ws [NWG] zeroed (epoch flags)
{
    __shared__ float svh[HID];   // staged h_t
    __shared__ float gacc[16];   // [q][jh]
    __shared__ float bsum[16];

    const int tid  = threadIdx.x;
    const int wg   = blockIdx.x;
    const int hbase = wg * HPW;
    const int lane = tid & 63;
    const int wv   = tid >> 6;   // gate index q

    // --- load this lane's weight slice into registers (once) ---
    float4 wr[4][6];
    #pragma unroll
    for (int jh = 0; jh < 4; ++jh) {
        const int row = wv * HID + hbase + jh;
        #pragma unroll
        for (int c = 0; c < 6; ++c) {
            const int k = lane * 4 + c * 256;
            wr[jh][c] = (k < IN)
                ? *(const float4*)&W_ih[(size_t)row * IN + k]
                : *(const float4*)&W_hh[(size_t)row * HID + (k - IN)];
        }
    }
    if (tid < 16) {
        const int q = tid >> 2, jh = tid & 3;
        const int row = q * HID + hbase + jh;
        bsum[tid] = b_ih[row] + b_hh[row];
    }
    float c_state = (tid < HPW) ? c0[hbase + tid] : 0.f;
    __syncthreads();

    for (int t = 0; t < T_STEPS; ++t) {
        // x slice straight to registers (issued before the poll: latency overlap)
        const float* xr = X + (size_t)t * IN;
        const float4 x0 = *(const float4*)&xr[lane * 4];
        const float4 x1 = *(const float4*)&xr[lane * 4 + 256];

        // wait for all WGs to have published h_t (epoch flags, read-only poll)
        if (t > 0) {
            const unsigned want = (unsigned)t;
            unsigned spins = 0;
            int ok;
            do {
                const unsigned v = __hip_atomic_load(&done[tid], __ATOMIC_RELAXED,
                                                     __HIP_MEMORY_SCOPE_AGENT);
                const int timeout = (++spins > 2000000u);  // ~0.5s: fail, don't hang
                ok = __syncthreads_and((int)(v >= want) | timeout);
            } while (!ok);
            asm volatile("" ::: "memory");
        }

        // stage h_t into LDS (uncached agent loads -> fresh from MALL)
        const float* hsrc = (t == 0) ? h0 : (hbuf + (size_t)(t & 1) * HID);
        #pragma unroll
        for (int j = 0; j < 4; ++j)
            svh[j * 256 + tid] = __hip_atomic_load(const_cast<float*>(&hsrc[j * 256 + tid]),
                                                   __ATOMIC_RELAXED, __HIP_MEMORY_SCOPE_AGENT);
        __syncthreads();

        // GEMV: 4 rows/wave, 24 elems/lane/row, weights in regs
        const float4 s2 = *(const float4*)&svh[lane * 4];
        const float4 s3 = *(const float4*)&svh[lane * 4 + 256];
        const float4 s4 = *(const float4*)&svh[lane * 4 + 512];
        const float4 s5 = *(const float4*)&svh[lane * 4 + 768];
        float a[4];
        #pragma unroll
        for (int jh = 0; jh < 4; ++jh) {
            const float4 w0 = wr[jh][0], w1 = wr[jh][1], w2 = wr[jh][2];
            const float4 w3 = wr[jh][3], w4 = wr[jh][4], w5 = wr[jh][5];
            float acc;
            acc  = w0.x*x0.x + w0.y*x0.y + w0.z*x0.z + w0.w*x0.w;
            acc += w1.x*x1.x + w1.y*x1.y + w1.z*x1.z + w1.w*x1.w;
            acc += w2.x*s2.x + w2.y*s2.y + w2.z*s2.z + w2.w*s2.w;
            acc += w3.x*s3.x + w3.y*s3.y + w3.z*s3.z + w3.w*s3.w;
            acc += w4.x*s4.x + w4.y*s4.y + w4.z*s4.z + w4.w*s4.w;
            acc += w5.x*s5.x + w5.y*s5.y + w5.z*s5.z + w5.w*s5.w;
            a[jh] = acc;
        }
        #pragma unroll
        for (int jh = 0; jh < 4; ++jh) {
            float v = a[jh];
            #pragma unroll
            for (int off = 32; off; off >>= 1) v += __shfl_xor(v, off);
            a[jh] = v;
        }
        if (lane == 0) {
            gacc[wv * 4 + 0] = a[0];
            gacc[wv * 4 + 1] = a[1];
            gacc[wv * 4 + 2] = a[2];
            gacc[wv * 4 + 3] = a[3];
        }
        __syncthreads();

        if (tid < HPW) {
            const float iv = sigmoidf_(gacc[ 0 + tid] + bsum[ 0 + tid]);
            const float fv = sigmoidf_(gacc[ 4 + tid] + bsum[ 4 + tid]);
            const float gv = tanhf   (gacc[ 8 + tid] + bsum[ 8 + tid]);
            const float ov = sigmoidf_(gacc[12 + tid] + bsum[12 + tid]);
            c_state = fv * c_state + iv * gv;
            const float h = ov * tanhf(c_state);
            h_all[(size_t)t * HID + hbase + tid] = h;
            __hip_atomic_store(&hbuf[(size_t)((t + 1) & 1) * HID + hbase + tid], h,
                               __ATOMIC_RELAXED, __HIP_MEMORY_SCOPE_AGENT);
        }
        if (tid < 64) {  // wave 0: order h stores (write-through, at MALL) before flag
            asm volatile("s_waitcnt vmcnt(0)" ::: "memory");
            if (tid == 0)
                __hip_atomic_store(&done[wg], (unsigned)(t + 1), __ATOMIC_RELAXED,
                                   __HIP_MEMORY_SCOPE_AGENT);
        }
        // no trailing __syncthreads: next iteration's poll is the rendezvous;
        // svh/gacc are only rewritten after all waves pass that poll.
    }
}

// ---------------- Kernel 2: out_t = softmax_C(h_t @ Wd^T + bd) ----------------
__global__ __launch_bounds__(256) void dense_softmax(
    const float* __restrict__ h_all, const float* __restrict__ Wd,
    const float* __restrict__ bd, float* __restrict__ P)
{
    __shared__ float hs[TT][HID];   // 32 KB
    __shared__ float ls[TT][NC];    // 16 KB
    const int tid = threadIdx.x;
    const int t0  = blockIdx.x * TT;

    for (int i = tid; i < TT * HID; i += 256)
        hs[i >> 10][i & 1023] = h_all[(size_t)t0 * HID + i];
    __syncthreads();

    const int c0 = tid, c1 = tid + 256;
    float acc0[TT], acc1[TT];
    #pragma unroll
    for (int tt = 0; tt < TT; ++tt) { acc0[tt] = 0.f; acc1[tt] = 0.f; }
    const float4* w0 = (const float4*)&Wd[(size_t)c0 * HID];
    const float4* w1 = (const float4*)&Wd[(size_t)c1 * HID];
    for (int k4 = 0; k4 < HID / 4; ++k4) {
        const float4 a = w0[k4], b = w1[k4];
        #pragma unroll
        for (int tt = 0; tt < TT; ++tt) {
            const float4 h4 = *(const float4*)&hs[tt][k4 * 4];
            acc0[tt] += a.x * h4.x + a.y * h4.y + a.z * h4.z + a.w * h4.w;
            acc1[tt] += b.x * h4.x + b.y * h4.y + b.z * h4.z + b.w * h4.w;
        }
    }
    const float bb0 = bd[c0], bb1 = bd[c1];
    #pragma unroll
    for (int tt = 0; tt < TT; ++tt) { ls[tt][c0] = acc0[tt] + bb0; ls[tt][c1] = acc1[tt] + bb1; }
    __syncthreads();

    const int lane = tid & 63, wv = tid >> 6;
    for (int rr = 0; rr < 2; ++rr) {
        const int tt = wv + rr * 4;
        float vals[8];
        float m = -1e30f;
        #pragma unroll
        for (int j = 0; j < 8; ++j) { vals[j] = ls[tt][lane + 64 * j]; m = fmaxf(m, vals[j]); }
        #pragma unroll
        for (int off = 32; off; off >>= 1) m = fmaxf(m, __shfl_xor(m, off));
        float s = 0.f;
        #pragma unroll
        for (int j = 0; j < 8; ++j) { vals[j] = expf(vals[j] - m); s += vals[j]; }
        #pragma unroll
        for (int off = 32; off; off >>= 1) s += __shfl_xor(s, off);
        const float inv = 1.f / s;
        #pragma unroll
        for (int j = 0; j < 8; ++j) P[(size_t)(t0 + tt) * NC + lane + 64 * j] = vals[j] * inv;
    }
}

// ---------------- Kernel 3a: colsum[c] = sum_t exp(P[t][c]) ----------------
__global__ __launch_bounds__(256) void colsum_k(const float* __restrict__ P, float* __restrict__ cs)
{
    const int tid = threadIdx.x;
    const int c  = blockIdx.x * 16 + (tid & 15);
    const int tr = tid >> 4;
    float s = 0.f;
    #pragma unroll 8
    for (int t = tr; t < T_STEPS; t += 16) s += expf(P[(size_t)t * NC + c]);
    __shared__ float red[256];
    red[tid] = s; __syncthreads();
    for (int off = 128; off >= 16; off >>= 1) {
        if (tid < off) red[tid] += red[tid + off];
        __syncthreads();
    }
    if (tid < 16) cs[blockIdx.x * 16 + tid] = red[tid];
}

// ---------------- Kernel 3b: out = exp(P) / colsum ----------------
__global__ __launch_bounds__(256) void norm_k(float* P, const float* __restrict__ cs)
{
    size_t i = (size_t)blockIdx.x * 256 + threadIdx.x;
    const size_t n = (size_t)T_STEPS * NC;
    const size_t stride = (size_t)gridDim.x * 256;
    for (; i < n; i += stride) P[i] = expf(P[i]) / cs[i & (NC - 1)];
}

extern "C" void kernel_launch(void* const* d_in, const int* in_sizes, int n_in,
                              void* d_out, int out_size, void* d_ws, size_t ws_size,
                              hipStream_t stream) {
    const float* X    = (const float*)d_in[0];
    const float* h0   = (const float*)d_in[1];
    const float* c0   = (const float*)d_in[2];
    const float* W_ih = (const float*)d_in[3];
    const float* W_hh = (const float*)d_in[4];
    const float* b_ih = (const float*)d_in[5];
    const float* b_hh = (const float*)d_in[6];
    const float* Wd   = (const float*)d_in[7];
    const float* bd   = (const float*)d_in[8];
    float* out = (float*)d_out;

    char* ws = (char*)d_ws;
    unsigned int* done = (unsigned int*)ws;            // [NWG] epoch flags
    float* hbuf  = (float*)(ws + 1024);                // [2, HID]
    float* cs    = (float*)(ws + 1024 + 8192);         // [NC]
    float* h_all = (float*)(ws + 16384);               // [T, HID]

    hipMemsetAsync(done, 0, 1024, stream);
    lstm_rec<<<NWG, TPB, 0, stream>>>(X, h0, c0, W_ih, W_hh, b_ih, b_hh, h_all, hbuf, done);
    dense_softmax<<<T_STEPS / TT, 256, 0, stream>>>(h_all, Wd, bd, out);
    colsum_k<<<NC / 16, 256, 0, stream>>>(out, cs);
    norm_k<<<2048, 256, 0, stream>>>(out, cs);
}

// Round 3
// 84297.211 us; speedup vs baseline: 3.1790x; 1.0220x over previous
//
#include <hip/hip_runtime.h>
#include <math.h>

#define T_STEPS 16384
#define IN 512
#define HID 1024
#define NC 512
#define NWG 256
#define TPB 256
#define TT 8            // t-rows per block in dense kernel

typedef unsigned long long ull;

__device__ __forceinline__ float sigmoidf_(float x) { return 1.f / (1.f + expf(-x)); }

// ---------------- Kernel 0: seed epoch-tagged h buffers ----------------
// bufp[p][j] = {epoch:u32 (hi), h:f32 (lo)}. h0 seeded with epoch 0 in parity 0;
// parity 1 cleared (ws is NOT re-poisoned between timed replays -> must reset).
__global__ void init_k(const float* __restrict__ h0, ull* __restrict__ bufp)
{
    const int j = threadIdx.x;          // 1024 threads, 1 block
    bufp[j]       = (ull)__float_as_uint(h0[j]);   // epoch 0 | h0
    bufp[HID + j] = 0ull;                          // epoch 0 | dummy
}

// ---------------- Kernel 1: persistent LSTM recurrence ----------------
// 256 WGs x 256 threads (4 waves). Wave wv of WG wg owns h element
// j = wg*4+wv and ALL FOUR of its gate rows (q*HID+j, q=0..3): the i/f/g/o
// combine is an intra-wave shuffle reduce -> lane 0, no LDS round trip.
// Weights in VGPRs: lane L holds k = L*4 + c*256, c=0..5 (c<2: x, c>=2: h).
// h published as a single 8B {epoch|h} atomic store; readers poll the data
// words directly (flag==data: one MALL round trip for detect+fetch).
__global__ __launch_bounds__(TPB, 1) void lstm_rec(
    const float* __restrict__ X,     // [T, IN]
    const float* __restrict__ c0,    // [HID]
    const float* __restrict__ W_ih,  // [4H, IN]
    const float* __restrict__ W_hh,  // [4H, HID]
    const float* __restrict__ b_ih,  // [4H]
    const float* __restrict__ b_hh,  // [4H]
    float* __restrict__ h_all,       // ws [T, HID]
    ull* __restrict__ bufp)          // ws [2][HID] epoch-tagged h
{
    __shared__ float svh[HID];

    const int tid  = threadIdx.x;
    const int wg   = blockIdx.x;
    const int lane = tid & 63;
    const int wv   = tid >> 6;
    const int j    = wg * 4 + wv;    // this wave's h element

    // --- weights for the 4 gate rows of element j, in registers ---
    float4 wr[4][6];
    float bias[4];
    #pragma unroll
    for (int q = 0; q < 4; ++q) {
        const int row = q * HID + j;
        #pragma unroll
        for (int c = 0; c < 6; ++c) {
            const int k = lane * 4 + c * 256;
            wr[q][c] = (k < IN)
                ? *(const float4*)&W_ih[(size_t)row * IN + k]
                : *(const float4*)&W_hh[(size_t)row * HID + (k - IN)];
        }
        bias[q] = b_ih[row] + b_hh[row];
    }
    float c_state = c0[j];   // only lane 0's copy is used

    for (int t = 0; t < T_STEPS; ++t) {
        // x slice to registers (overlaps the poll)
        const float* xr = X + (size_t)t * IN;
        const float4 x0 = *(const float4*)&xr[lane * 4];
        const float4 x1 = *(const float4*)&xr[lane * 4 + 256];

        // poll h_{t-1}: epoch-tagged words, selective re-load of stale entries
        const ull* src = bufp + (size_t)(t & 1) * HID;
        const unsigned want = (unsigned)t;
        ull v[4];
        #pragma unroll
        for (int c = 0; c < 4; ++c)
            v[c] = __hip_atomic_load(const_cast<ull*>(&src[tid + 256 * c]),
                                     __ATOMIC_RELAXED, __HIP_MEMORY_SCOPE_AGENT);
        unsigned spins = 0;
        int ok;
        do {
            bool all = true;
            #pragma unroll
            for (int c = 0; c < 4; ++c) {
                if ((unsigned)(v[c] >> 32) < want)
                    v[c] = __hip_atomic_load(const_cast<ull*>(&src[tid + 256 * c]),
                                             __ATOMIC_RELAXED, __HIP_MEMORY_SCOPE_AGENT);
                all &= ((unsigned)(v[c] >> 32) >= want);
            }
            #pragma unroll
            for (int c = 0; c < 4; ++c)
                svh[tid + 256 * c] = __uint_as_float((unsigned)v[c]);
            const int timeout = (++spins > 3000000u);   // fail, don't hang
            ok = __syncthreads_and((int)all | timeout);
        } while (!ok);

        // GEMV: 4 gate rows of element j, weights in regs, h from LDS
        const float4 s2 = *(const float4*)&svh[lane * 4];
        const float4 s3 = *(const float4*)&svh[lane * 4 + 256];
        const float4 s4 = *(const float4*)&svh[lane * 4 + 512];
        const float4 s5 = *(const float4*)&svh[lane * 4 + 768];
        __syncthreads();   // all waves consumed svh -> next iter may overwrite

        float a[4];
        #pragma unroll
        for (int q = 0; q < 4; ++q) {
            const float4 w0 = wr[q][0], w1 = wr[q][1], w2 = wr[q][2];
            const float4 w3 = wr[q][3], w4 = wr[q][4], w5 = wr[q][5];
            float acc;
            acc  = w0.x*x0.x + w0.y*x0.y + w0.z*x0.z + w0.w*x0.w;
            acc += w1.x*x1.x + w1.y*x1.y + w1.z*x1.z + w1.w*x1.w;
            acc += w2.x*s2.x + w2.y*s2.y + w2.z*s2.z + w2.w*s2.w;
            acc += w3.x*s3.x + w3.y*s3.y + w3.z*s3.z + w3.w*s3.w;
            acc += w4.x*s4.x + w4.y*s4.y + w4.z*s4.z + w4.w*s4.w;
            acc += w5.x*s5.x + w5.y*s5.y + w5.z*s5.z + w5.w*s5.w;
            a[q] = acc;
        }
        #pragma unroll
        for (int q = 0; q < 4; ++q) {
            float s = a[q];
            #pragma unroll
            for (int off = 32; off; off >>= 1) s += __shfl_xor(s, off);
            a[q] = s;
        }

        if (lane == 0) {
            const float iv = sigmoidf_(a[0] + bias[0]);
            const float fv = sigmoidf_(a[1] + bias[1]);
            const float gv = tanhf   (a[2] + bias[2]);
            const float ov = sigmoidf_(a[3] + bias[3]);
            c_state = fv * c_state + iv * gv;
            const float h = ov * tanhf(c_state);
            h_all[(size_t)t * HID + j] = h;
            const ull pv = ((ull)(unsigned)(t + 1) << 32) | (ull)__float_as_uint(h);
            __hip_atomic_store(&bufp[(size_t)((t + 1) & 1) * HID + j], pv,
                               __ATOMIC_RELAXED, __HIP_MEMORY_SCOPE_AGENT);
        }
    }
}

// ---------------- Kernel 2: out_t = softmax_C(h_t @ Wd^T + bd) ----------------
__global__ __launch_bounds__(256) void dense_softmax(
    const float* __restrict__ h_all, const float* __restrict__ Wd,
    const float* __restrict__ bd, float* __restrict__ P)
{
    __shared__ float hs[TT][HID];   // 32 KB
    __shared__ float ls[TT][NC];    // 16 KB
    const int tid = threadIdx.x;
    const int t0  = blockIdx.x * TT;

    for (int i = tid; i < TT * HID; i += 256)
        hs[i >> 10][i & 1023] = h_all[(size_t)t0 * HID + i];
    __syncthreads();

    const int c0 = tid, c1 = tid + 256;
    float acc0[TT], acc1[TT];
    #pragma unroll
    for (int tt = 0; tt < TT; ++tt) { acc0[tt] = 0.f; acc1[tt] = 0.f; }
    const float4* w0 = (const float4*)&Wd[(size_t)c0 * HID];
    const float4* w1 = (const float4*)&Wd[(size_t)c1 * HID];
    for (int k4 = 0; k4 < HID / 4; ++k4) {
        const float4 a = w0[k4], b = w1[k4];
        #pragma unroll
        for (int tt = 0; tt < TT; ++tt) {
            const float4 h4 = *(const float4*)&hs[tt][k4 * 4];
            acc0[tt] += a.x * h4.x + a.y * h4.y + a.z * h4.z + a.w * h4.w;
            acc1[tt] += b.x * h4.x + b.y * h4.y + b.z * h4.z + b.w * h4.w;
        }
    }
    const float bb0 = bd[c0], bb1 = bd[c1];
    #pragma unroll
    for (int tt = 0; tt < TT; ++tt) { ls[tt][c0] = acc0[tt] + bb0; ls[tt][c1] = acc1[tt] + bb1; }
    __syncthreads();

    const int lane = tid & 63, wv = tid >> 6;
    for (int rr = 0; rr < 2; ++rr) {
        const int tt = wv + rr * 4;
        float vals[8];
        float m = -1e30f;
        #pragma unroll
        for (int jx = 0; jx < 8; ++jx) { vals[jx] = ls[tt][lane + 64 * jx]; m = fmaxf(m, vals[jx]); }
        #pragma unroll
        for (int off = 32; off; off >>= 1) m = fmaxf(m, __shfl_xor(m, off));
        float s = 0.f;
        #pragma unroll
        for (int jx = 0; jx < 8; ++jx) { vals[jx] = expf(vals[jx] - m); s += vals[jx]; }
        #pragma unroll
        for (int off = 32; off; off >>= 1) s += __shfl_xor(s, off);
        const float inv = 1.f / s;
        #pragma unroll
        for (int jx = 0; jx < 8; ++jx) P[(size_t)(t0 + tt) * NC + lane + 64 * jx] = vals[jx] * inv;
    }
}

// ---------------- Kernel 3a: colsum[c] = sum_t exp(P[t][c]) ----------------
__global__ __launch_bounds__(256) void colsum_k(const float* __restrict__ P, float* __restrict__ cs)
{
    const int tid = threadIdx.x;
    const int c  = blockIdx.x * 16 + (tid & 15);
    const int tr = tid >> 4;
    float s = 0.f;
    #pragma unroll 8
    for (int t = tr; t < T_STEPS; t += 16) s += expf(P[(size_t)t * NC + c]);
    __shared__ float red[256];
    red[tid] = s; __syncthreads();
    for (int off = 128; off >= 16; off >>= 1) {
        if (tid < off) red[tid] += red[tid + off];
        __syncthreads();
    }
    if (tid < 16) cs[blockIdx.x * 16 + tid] = red[tid];
}

// ---------------- Kernel 3b: out = exp(P) / colsum ----------------
__global__ __launch_bounds__(256) void norm_k(float* P, const float* __restrict__ cs)
{
    size_t i = (size_t)blockIdx.x * 256 + threadIdx.x;
    const size_t n = (size_t)T_STEPS * NC;
    const size_t stride = (size_t)gridDim.x * 256;
    for (; i < n; i += stride) P[i] = expf(P[i]) / cs[i & (NC - 1)];
}

extern "C" void kernel_launch(void* const* d_in, const int* in_sizes, int n_in,
                              void* d_out, int out_size, void* d_ws, size_t ws_size,
                              hipStream_t stream) {
    const float* X    = (const float*)d_in[0];
    const float* h0   = (const float*)d_in[1];
    const float* c0   = (const float*)d_in[2];
    const float* W_ih = (const float*)d_in[3];
    const float* W_hh = (const float*)d_in[4];
    const float* b_ih = (const float*)d_in[5];
    const float* b_hh = (const float*)d_in[6];
    const float* Wd   = (const float*)d_in[7];
    const float* bd   = (const float*)d_in[8];
    float* out = (float*)d_out;

    char* ws = (char*)d_ws;
    ull*   bufp  = (ull*)ws;                     // [2][HID] epoch|h
    float* cs    = (float*)(ws + 16384);         // [NC]
    float* h_all = (float*)(ws + 32768);         // [T, HID]

    init_k<<<1, HID, 0, stream>>>(h0, bufp);
    lstm_rec<<<NWG, TPB, 0, stream>>>(X, c0, W_ih, W_hh, b_ih, b_hh, h_all, bufp);
    dense_softmax<<<T_STEPS / TT, 256, 0, stream>>>(h_all, Wd, bd, out);
    colsum_k<<<NC / 16, 256, 0, stream>>>(out, cs);
    norm_k<<<2048, 256, 0, stream>>>(out, cs);
}